// Round 9
// baseline (543.985 us; speedup 1.0000x reference)
//
#include <hip/hip_runtime.h>
#include <hip/hip_bf16.h>

typedef __hip_bfloat16 bf16;
typedef __attribute__((ext_vector_type(8))) __bf16 bf16x8;
typedef __attribute__((ext_vector_type(4))) float f32x4;
typedef unsigned int u32;

#define HW 16384

static __device__ __forceinline__ float b2f(bf16 v) { return __bfloat162float(v); }
static __device__ __forceinline__ bf16 f2b(float v) { return __float2bfloat16(v); }
static __device__ __forceinline__ float blo(unsigned int w) {
    return __uint_as_float(w << 16);
}
static __device__ __forceinline__ float bhi(unsigned int w) {
    return __uint_as_float(w & 0xffff0000u);
}
static __device__ __forceinline__ unsigned short f2bu(float v) {
    union { bf16 b; unsigned short u; } c; c.b = f2b(v); return c.u;
}

static __device__ __forceinline__ void stf(float* p, float v) { *p = v; }
static __device__ __forceinline__ void stf(bf16* p, float v)  { *p = f2b(v); }

// async global->LDS, 16B per lane; LDS dest = wave-uniform base + lane*16
static __device__ __forceinline__ void gload_lds16(const void* g, void* l) {
    __builtin_amdgcn_global_load_lds(
        (const __attribute__((address_space(1))) void*)g,
        (__attribute__((address_space(3))) void*)l, 16, 0, 0);
}

// load 8 consecutive values as f32 (16B- or 32B-vectorized)
static __device__ __forceinline__ void load8(const float* p, float* v) {
    const float4* q = (const float4*)p;
    float4 a = q[0], b = q[1];
    v[0] = a.x; v[1] = a.y; v[2] = a.z; v[3] = a.w;
    v[4] = b.x; v[5] = b.y; v[6] = b.z; v[7] = b.w;
}
static __device__ __forceinline__ void load8(const bf16* p, float* v) {
    uint4 u = *(const uint4*)p;
    v[0] = blo(u.x); v[1] = bhi(u.x); v[2] = blo(u.y); v[3] = bhi(u.y);
    v[4] = blo(u.z); v[5] = bhi(u.z); v[6] = blo(u.w); v[7] = bhi(u.w);
}

// ============ P0: transpose+cast x: f32 [b][192][16384] -> bf16 [b][16384][192]
__global__ __launch_bounds__(256) void tr_cast(
    const float* __restrict__ x, bf16* __restrict__ xT)
{
    const int b  = blockIdx.x >> 8;
    const int t  = blockIdx.x & 255;
    const int hw0 = t << 6;                       // 64-col slab
    const float* xb = x + (size_t)b * 192 * HW;

    __shared__ unsigned short T[64][200];         // [hw][c], 400B rows

    const int tid = threadIdx.x;
    for (int i = tid; i < 192 * 16; i += 256) {   // 192 rows x 16 float4
        int c = i >> 4, seg = i & 15;
        float4 f = *(const float4*)(xb + (size_t)c * HW + hw0 + seg * 4);
        T[seg * 4 + 0][c] = f2bu(f.x);
        T[seg * 4 + 1][c] = f2bu(f.y);
        T[seg * 4 + 2][c] = f2bu(f.z);
        T[seg * 4 + 3][c] = f2bu(f.w);
    }
    __syncthreads();

    const int hw = tid >> 2, c0 = (tid & 3) * 48; // 96 B per thread
    const uint4* src = (const uint4*)&T[hw][c0];
    uint4* dst = (uint4*)(xT + ((size_t)(b * HW) + hw0 + hw) * 192 + c0);
#pragma unroll
    for (int j = 0; j < 6; j++) dst[j] = src[j];
}

// ============ P1: cast f32 weights -> bf16 (tiny) ===========================
__global__ __launch_bounds__(256) void wcast(
    const float* __restrict__ w, bf16* __restrict__ o, int n4)
{
    int i = blockIdx.x * 256 + threadIdx.x;
    if (i < n4) {
        float4 f = ((const float4*)w)[i];
        u32 lo = (u32)f2bu(f.x) | ((u32)f2bu(f.y) << 16);
        u32 hi = (u32)f2bu(f.z) | ((u32)f2bu(f.w) << 16);
        ((uint2*)o)[i] = make_uint2(lo, hi);
    }
}

// ============ K1/K7: gload_lds MFMA GEMM Y[b] = W(Mx192) @ X[b](192xN) ======
// (unchanged from R8 — verified: MfmaUtil 13%, 2.05 TB/s)
template <typename TY>
__global__ __launch_bounds__(256) void gemm_mfma(
    const bf16* __restrict__ Wb, const bf16* __restrict__ Bx,
    TY* __restrict__ Y, int MB)
{
    constexpr int N = HW;
    const int b    = blockIdx.x & 7;
    const int slot = blockIdx.x >> 3;
    const int mb   = slot % MB;
    const int ng   = slot / MB;            // 0..127
    const int m0   = mb * 64;
    const int n0   = ng * 128;

    const char* Bpanel = (const char*)(Bx + (size_t)b * N * 192) + (size_t)n0 * 384;
    TY* Yb = Y + (size_t)b * (MB * 64) * N;

    __shared__ __align__(16) char Bs[49152];   // 128 rows x 384 B, swizzled

    const int tid  = threadIdx.x;
    const int lane = tid & 63, wave = tid >> 6;
    const int wm = (wave & 1) * 32, wn = (wave >> 1) * 64;
    const int r16 = lane & 15, quad = lane >> 4;

    // ---- stage B: 12 rounds x 4KB; source pre-swizzled (rule #21) ----
#pragma unroll
    for (int r = 0; r < 12; r++) {
        int L   = r * 4096 + tid * 16;         // linear LDS byte this lane fills
        int row = L / 384;
        int col = L - row * 384;
        int scol = col ^ ((row & 7) << 4);     // involution, stays in-row
        gload_lds16(Bpanel + (size_t)row * 384 + scol,
                    Bs + r * 4096 + wave * 1024);
    }

    // ---- A (weights) -> registers (L1/L2-hot, tiny) ----
    const bf16* aBase = Wb + (size_t)(m0 + wm + r16) * 192 + quad * 8;
    bf16x8 aReg[6][2];
#pragma unroll
    for (int ks = 0; ks < 6; ks++)
#pragma unroll
        for (int h = 0; h < 2; h++)
            aReg[ks][h] = *(const bf16x8*)(aBase + h * 16 * 192 + ks * 32);

    asm volatile("s_waitcnt vmcnt(0)" ::: "memory");   // drain gload_lds queue
    __syncthreads();

    f32x4 acc[2][4];
#pragma unroll
    for (int i = 0; i < 2; i++)
#pragma unroll
        for (int j = 0; j < 4; j++) acc[i][j] = (f32x4){0.f, 0.f, 0.f, 0.f};

    // per-sn row base + swizzle phase
    int rbase[4], rxor[4];
#pragma unroll
    for (int sn = 0; sn < 4; sn++) {
        int nl = wn + sn * 16 + r16;
        rbase[sn] = nl * 384;
        rxor[sn]  = (nl & 7) << 4;
    }

#pragma unroll
    for (int ks = 0; ks < 6; ks++) {
#pragma unroll
        for (int sn = 0; sn < 4; sn++) {
            bf16x8 bb = *(const bf16x8*)(
                Bs + rbase[sn] + ((ks * 64 + quad * 16) ^ rxor[sn]));
            acc[0][sn] = __builtin_amdgcn_mfma_f32_16x16x32_bf16(
                aReg[ks][0], bb, acc[0][sn], 0, 0, 0);
            acc[1][sn] = __builtin_amdgcn_mfma_f32_16x16x32_bf16(
                aReg[ks][1], bb, acc[1][sn], 0, 0, 0);
        }
    }

    // epilogue: C/D layout col=lane&15 (n), row=quad*4+reg (m) [m89/m91]
#pragma unroll
    for (int sm = 0; sm < 2; sm++)
#pragma unroll
        for (int sn = 0; sn < 4; sn++) {
            const int gr = m0 + wm + sm * 16 + quad * 4;
            const int gc = n0 + wn + sn * 16 + r16;
#pragma unroll
            for (int r = 0; r < 4; r++)
                stf(Yb + (size_t)(gr + r) * N + gc, acc[sm][sn][r]);
        }
}

// ============ K2: depthwise 3x3, pad 1 — LDS-tiled, vectorized ==============
__global__ __launch_bounds__(256) void dwconv3x3(
    const bf16* __restrict__ in, const float* __restrict__ wdw,
    bf16* __restrict__ out)
{
    const int plane = blockIdx.x >> 2;          // b*576 + c
    const int ybase = (blockIdx.x & 3) << 5;    // 0,32,64,96
    const int c = plane % 576;
    const bf16* ip = in + ((size_t)plane << 14);

    __shared__ unsigned short Ls[34][128];

    for (int i = threadIdx.x; i < 34 * 16; i += 256) {
        int r = i >> 4, cx = i & 15;
        int y = ybase - 1 + r;
        uint4 v = make_uint4(0u, 0u, 0u, 0u);
        if (y >= 0 && y < 128) v = ((const uint4*)(ip + ((size_t)y << 7)))[cx];
        ((uint4*)Ls[r])[cx] = v;
    }

    float w[9];
#pragma unroll
    for (int i = 0; i < 9; i++) w[i] = wdw[c * 9 + i];

    __syncthreads();

    const int lr = threadIdx.x >> 3;         // 0..31 output row
    const int c0 = (threadIdx.x & 7) << 4;   // 0,16,..,112

    float row[3][18];
#pragma unroll
    for (int r3 = 0; r3 < 3; r3++) {
        int rr = lr + r3;
        row[r3][0]  = c0 ? __uint_as_float((unsigned int)Ls[rr][c0 - 1] << 16) : 0.f;
        row[r3][17] = (c0 + 16 < 128) ? __uint_as_float((unsigned int)Ls[rr][c0 + 16] << 16) : 0.f;
        const uint4* rp = (const uint4*)&Ls[rr][c0];
        uint4 p0 = rp[0], p1 = rp[1];
        row[r3][1] = blo(p0.x); row[r3][2] = bhi(p0.x);
        row[r3][3] = blo(p0.y); row[r3][4] = bhi(p0.y);
        row[r3][5] = blo(p0.z); row[r3][6] = bhi(p0.z);
        row[r3][7] = blo(p0.w); row[r3][8] = bhi(p0.w);
        row[r3][9]  = blo(p1.x); row[r3][10] = bhi(p1.x);
        row[r3][11] = blo(p1.y); row[r3][12] = bhi(p1.y);
        row[r3][13] = blo(p1.z); row[r3][14] = bhi(p1.z);
        row[r3][15] = blo(p1.w); row[r3][16] = bhi(p1.w);
    }

    union { unsigned short s[16]; uint4 v[2]; } o;
#pragma unroll
    for (int j = 0; j < 16; j++) {
        float s = 0.f;
#pragma unroll
        for (int r3 = 0; r3 < 3; r3++)
            s += w[r3 * 3 + 0] * row[r3][j] + w[r3 * 3 + 1] * row[r3][j + 1]
               + w[r3 * 3 + 2] * row[r3][j + 2];
        o.s[j] = f2bu(s);
    }
    uint4* op = (uint4*)(out + ((size_t)plane << 14) + ((size_t)(ybase + lr) << 7) + c0);
    op[0] = o.v[0];
    op[1] = o.v[1];
}

// ============ K3: per-row inverse L2 norm (q rows then k rows) ==============
__global__ __launch_bounds__(256) void rownorm(
    const bf16* __restrict__ qkv, float* __restrict__ rn)
{
    int r = blockIdx.x;
    int which = (r >= 1536) ? 1 : 0;
    int rr = r - which * 1536;
    int b = rr / 192, c = rr % 192;
    const bf16* p = qkv + ((size_t)(b * 576 + which * 192 + c) << 14);

    float s = 0.f;
    for (int i = threadIdx.x * 8; i < HW; i += 256 * 8) {
        float v[8];
        load8(p + i, v);
#pragma unroll
        for (int j = 0; j < 8; j++) s += v[j] * v[j];
    }
#pragma unroll
    for (int off = 32; off; off >>= 1) s += __shfl_down(s, off);
    __shared__ float red[4];
    if ((threadIdx.x & 63) == 0) red[threadIdx.x >> 6] = s;
    __syncthreads();
    if (threadIdx.x == 0) {
        float t = red[0] + red[1] + red[2] + red[3];
        rn[r] = 1.0f / fmaxf(sqrtf(t), 1e-12f);
    }
}

// ============ K4: raw dot products S[bh,c,d] = sum_n q[c,n]k[d,n] ===========
__global__ __launch_bounds__(256) void attn_dots(
    const bf16* __restrict__ qkv, float* __restrict__ attn)
{
    const int bh = blockIdx.y, b = bh >> 2, h = bh & 3;
    const int n0 = blockIdx.x * 1024;
    const bf16* q  = qkv + ((size_t)(b * 576 + h * 48) << 14);
    const bf16* kp = qkv + ((size_t)(b * 576 + 192 + h * 48) << 14);

    __shared__ float qt[48][68];
    __shared__ float kt[48][68];

    const int tid = threadIdx.x;
    const int cg = tid >> 4, dg = tid & 15;

    float acc[3][3] = {{0.f, 0.f, 0.f}, {0.f, 0.f, 0.f}, {0.f, 0.f, 0.f}};

    for (int s0 = 0; s0 < 1024; s0 += 64) {
        for (int i = tid; i < 48 * 8; i += 256) {
            int rowi = i / 8, cx = (i & 7) * 8;
            size_t off = ((size_t)rowi << 14) + n0 + s0 + cx;
            float v[8];
            load8(q + off, v);
#pragma unroll
            for (int j = 0; j < 8; j++) qt[rowi][cx + j] = v[j];
            load8(kp + off, v);
#pragma unroll
            for (int j = 0; j < 8; j++) kt[rowi][cx + j] = v[j];
        }
        __syncthreads();
#pragma unroll 8
        for (int n = 0; n < 64; n++) {
            float a0 = qt[cg * 3 + 0][n], a1 = qt[cg * 3 + 1][n], a2 = qt[cg * 3 + 2][n];
            float b0 = kt[dg * 3 + 0][n], b1 = kt[dg * 3 + 1][n], b2 = kt[dg * 3 + 2][n];
            acc[0][0] += a0 * b0; acc[0][1] += a0 * b1; acc[0][2] += a0 * b2;
            acc[1][0] += a1 * b0; acc[1][1] += a1 * b1; acc[1][2] += a1 * b2;
            acc[2][0] += a2 * b0; acc[2][1] += a2 * b1; acc[2][2] += a2 * b2;
        }
        __syncthreads();
    }
#pragma unroll
    for (int i = 0; i < 3; i++)
#pragma unroll
        for (int j = 0; j < 3; j++)
            atomicAdd(&attn[(size_t)bh * 2304 + (cg * 3 + i) * 48 + dg * 3 + j],
                      acc[i][j]);
}

// ============ K5: scale by norms & temperature, softmax over d ==============
__global__ __launch_bounds__(64) void softmax48(
    float* __restrict__ attn, const float* __restrict__ rn,
    const float* __restrict__ temp)
{
    int bh = blockIdx.x, b = bh >> 2, h = bh & 3;
    int c = threadIdx.x;
    if (c >= 48) return;
    float t = temp[h];
    float iq = rn[b * 192 + h * 48 + c];
    const float* ik = rn + 1536 + b * 192 + h * 48;
    float* row = attn + (size_t)bh * 2304 + c * 48;

    float v[48];
    float mx = -1e30f;
#pragma unroll
    for (int d = 0; d < 48; d++) {
        v[d] = row[d] * iq * ik[d] * t;
        mx = fmaxf(mx, v[d]);
    }
    float s = 0.f;
#pragma unroll
    for (int d = 0; d < 48; d++) {
        v[d] = expf(v[d] - mx);
        s += v[d];
    }
    float inv = 1.0f / s;
#pragma unroll
    for (int d = 0; d < 48; d++) row[d] = v[d] * inv;
}

// ============ K6: out^T[n][c] = sum_d attn[c,d] * v[d,n] ====================
// R8 post-mortem: VGPR_Count=64 showed the compiler serialized one output c
// at a time -> 48-deep dependent v_fmac chain (4cy each) + per-c scalar-load
// waits = VALUBusy 26%. v3:
//  - NO LDS: for fixed d, 64 lanes read 128 contiguous B of V -> direct
//    global_load_ushort is already dense (2 lines/instr). No barrier.
//  - c processed in 12 groups of 4 INDEPENDENT accumulators; per d one vd
//    feeds 4 fmacs (1 SGPR read each) -> issue-bound, not latency-bound.
//  - pack each group into pk immediately (all static idx, rule #20);
//    one 96B contiguous store per thread.
// Per-output accumulation order (d ascending) + even/odd c packing unchanged
// -> bitwise-identical numerics.
__global__ __launch_bounds__(256) void attn_v_t(
    const float* __restrict__ attn, const bf16* __restrict__ qkv,
    bf16* __restrict__ outT)
{
    const int nb = blockIdx.x;            // 0..63 (256-col slab)
    const int h  = blockIdx.y & 3;
    const int b  = blockIdx.y >> 2;
    const int n  = nb * 256 + threadIdx.x;

    const unsigned short* vp = (const unsigned short*)
        (qkv + ((size_t)(b * 576 + 384 + h * 48) << 14) + n);

    // 48 direct loads; per-wave each is 64 lanes x 2B contiguous (dense)
    float v[48];
#pragma unroll
    for (int d = 0; d < 48; d++)
        v[d] = blo((u32)vp[(size_t)d << 14]);

    // A row base: wave-uniform -> scalar loads on the scalar pipe
    const float* __restrict__ Ah = attn + (size_t)(b * 4 + h) * 2304;

    uint4 pk[6];
    u32* pw = (u32*)pk;
#pragma unroll
    for (int cg = 0; cg < 12; cg++) {
        const float* __restrict__ A0 = Ah + cg * 192;   // 4 rows of 48
        float a0 = 0.f, a1 = 0.f, a2 = 0.f, a3 = 0.f;
#pragma unroll
        for (int d = 0; d < 48; d++) {
            float vd = v[d];
            a0 += A0[d]       * vd;
            a1 += A0[48 + d]  * vd;
            a2 += A0[96 + d]  * vd;
            a3 += A0[144 + d] * vd;
        }
        pw[2 * cg]     = (u32)f2bu(a0) | ((u32)f2bu(a1) << 16);
        pw[2 * cg + 1] = (u32)f2bu(a2) | ((u32)f2bu(a3) << 16);
    }

    // 96B contiguous store at [n][h*48..h*48+48)
    bf16* o = outT + ((size_t)(b * HW) + n) * 192 + h * 48;
    uint4* d4 = (uint4*)o;
#pragma unroll
    for (int j = 0; j < 6; j++) d4[j] = pk[j];
}

// ============================================================================
extern "C" void kernel_launch(void* const* d_in, const int* in_sizes, int n_in,
                              void* d_out, int out_size, void* d_ws, size_t ws_size,
                              hipStream_t stream)
{
    const float* x      = (const float*)d_in[0];
    const float* qkv_w  = (const float*)d_in[1];
    const float* dw_w   = (const float*)d_in[2];
    const float* proj_w = (const float*)d_in[3];
    const float* temp   = (const float*)d_in[4];
    float* out = (float*)d_out;

    char* ws = (char*)d_ws;
    const size_t qkvBytes = (size_t)8 * 576 * HW * sizeof(bf16);  // 150,994,944 B
    bf16*  qkv0 = (bf16*)ws;                                  // pre-dw qkv
    bf16*  qkv1 = (bf16*)(ws + qkvBytes);                     // post-dw qkv
    float* attn = (float*)(ws + 2 * qkvBytes);                // 32*48*48 f32
    float* rn   = (float*)(ws + 2 * qkvBytes + (size_t)32 * 2304 * sizeof(float));

    // Aliases (footprint unchanged; all lifetimes disjoint):
    bf16* xT    = (bf16*)qkv1;               // 50.3 MB; dead once dwconv writes qkv1
    bf16* aoutT = (bf16*)qkv0;               // 50.3 MB; qkv0 dead after dwconv
    bf16* Wb    = (bf16*)attn;               // 221 KB < 294 KB; dead before memset
    bf16* Pb    = (bf16*)(ws + 100 * 1024 * 1024);  // in dead tail of qkv0 region

    // 0) transpose+cast x -> xT bf16 [b][n][k]
    tr_cast<<<dim3(8 * 256), 256, 0, stream>>>(x, xT);
    // 0b) cast qkv weights -> bf16
    wcast<<<dim3(108), 256, 0, stream>>>(qkv_w, Wb, 27648);
    // 1) qkv 1x1 conv (gload_lds MFMA): (576x192) @ (192x16384) per batch
    gemm_mfma<bf16><<<dim3(8 * 9 * 128), 256, 0, stream>>>(Wb, xT, qkv0, 9);
    // 2) depthwise 3x3 (LDS-tiled); overwrites xT region (dead)
    dwconv3x3<<<dim3(8 * 576 * 4), 256, 0, stream>>>(qkv0, dw_w, qkv1);
    // 2b) cast proj weights into dead qkv0 tail
    wcast<<<dim3(36), 256, 0, stream>>>(proj_w, Pb, 9216);
    // 3) inverse L2 norms for q and k rows
    rownorm<<<dim3(3072), 256, 0, stream>>>(qkv1, rn);
    // 4) attention dots (f32 atomics into zeroed buffer); clobbers Wb (dead)
    hipMemsetAsync(attn, 0, (size_t)32 * 2304 * sizeof(float), stream);
    attn_dots<<<dim3(16, 32), 256, 0, stream>>>(qkv1, attn);
    // 5) scale + softmax
    softmax48<<<dim3(32), 64, 0, stream>>>(attn, rn, temp);
    // 6) attn @ v -> transposed bf16 [b][n][192]
    attn_v_t<<<dim3(64, 32), 256, 0, stream>>>(attn, qkv1, aoutT);
    // 7) proj 1x1 conv (gload_lds MFMA): (192x192) @ (192x16384) per batch
    gemm_mfma<float><<<dim3(8 * 3 * 128), 256, 0, stream>>>(Pb, aoutT, out, 3);
}

// Round 10
// 504.979 us; speedup vs baseline: 1.0772x; 1.0772x over previous
//
#include <hip/hip_runtime.h>
#include <hip/hip_bf16.h>

typedef __hip_bfloat16 bf16;
typedef __attribute__((ext_vector_type(8))) __bf16 bf16x8;
typedef __attribute__((ext_vector_type(4))) float f32x4;
typedef unsigned int u32;

#define HW 16384

static __device__ __forceinline__ float b2f(bf16 v) { return __bfloat162float(v); }
static __device__ __forceinline__ bf16 f2b(float v) { return __float2bfloat16(v); }
static __device__ __forceinline__ float blo(unsigned int w) {
    return __uint_as_float(w << 16);
}
static __device__ __forceinline__ float bhi(unsigned int w) {
    return __uint_as_float(w & 0xffff0000u);
}
static __device__ __forceinline__ unsigned short f2bu(float v) {
    union { bf16 b; unsigned short u; } c; c.b = f2b(v); return c.u;
}

static __device__ __forceinline__ void stf(float* p, float v) { *p = v; }
static __device__ __forceinline__ void stf(bf16* p, float v)  { *p = f2b(v); }

// async global->LDS, 16B per lane; LDS dest = wave-uniform base + lane*16
static __device__ __forceinline__ void gload_lds16(const void* g, void* l) {
    __builtin_amdgcn_global_load_lds(
        (const __attribute__((address_space(1))) void*)g,
        (__attribute__((address_space(3))) void*)l, 16, 0, 0);
}

// load 8 consecutive values as f32 (16B- or 32B-vectorized)
static __device__ __forceinline__ void load8(const float* p, float* v) {
    const float4* q = (const float4*)p;
    float4 a = q[0], b = q[1];
    v[0] = a.x; v[1] = a.y; v[2] = a.z; v[3] = a.w;
    v[4] = b.x; v[5] = b.y; v[6] = b.z; v[7] = b.w;
}
static __device__ __forceinline__ void load8(const bf16* p, float* v) {
    uint4 u = *(const uint4*)p;
    v[0] = blo(u.x); v[1] = bhi(u.x); v[2] = blo(u.y); v[3] = bhi(u.y);
    v[4] = blo(u.z); v[5] = bhi(u.z); v[6] = blo(u.w); v[7] = bhi(u.w);
}

// ============ P0: transpose+cast x: f32 [b][192][16384] -> bf16 [b][16384][192]
__global__ __launch_bounds__(256) void tr_cast(
    const float* __restrict__ x, bf16* __restrict__ xT)
{
    const int b  = blockIdx.x >> 8;
    const int t  = blockIdx.x & 255;
    const int hw0 = t << 6;                       // 64-col slab
    const float* xb = x + (size_t)b * 192 * HW;

    __shared__ unsigned short T[64][200];         // [hw][c], 400B rows

    const int tid = threadIdx.x;
    for (int i = tid; i < 192 * 16; i += 256) {   // 192 rows x 16 float4
        int c = i >> 4, seg = i & 15;
        float4 f = *(const float4*)(xb + (size_t)c * HW + hw0 + seg * 4);
        T[seg * 4 + 0][c] = f2bu(f.x);
        T[seg * 4 + 1][c] = f2bu(f.y);
        T[seg * 4 + 2][c] = f2bu(f.z);
        T[seg * 4 + 3][c] = f2bu(f.w);
    }
    __syncthreads();

    const int hw = tid >> 2, c0 = (tid & 3) * 48; // 96 B per thread
    const uint4* src = (const uint4*)&T[hw][c0];
    uint4* dst = (uint4*)(xT + ((size_t)(b * HW) + hw0 + hw) * 192 + c0);
#pragma unroll
    for (int j = 0; j < 6; j++) dst[j] = src[j];
}

// ============ P1: cast f32 weights -> bf16 (tiny) ===========================
__global__ __launch_bounds__(256) void wcast(
    const float* __restrict__ w, bf16* __restrict__ o, int n4)
{
    int i = blockIdx.x * 256 + threadIdx.x;
    if (i < n4) {
        float4 f = ((const float4*)w)[i];
        u32 lo = (u32)f2bu(f.x) | ((u32)f2bu(f.y) << 16);
        u32 hi = (u32)f2bu(f.z) | ((u32)f2bu(f.w) << 16);
        ((uint2*)o)[i] = make_uint2(lo, hi);
    }
}

// ============ K1/K7: gload_lds MFMA GEMM Y[b] = W(Mx192) @ X[b](192xN) ======
// (structure verified R8: MfmaUtil 13%, 2.05 TB/s). wstride selects shared
// weights (0, qkv conv) or per-batch weights (192*192, merged attn+proj).
template <typename TY>
__global__ __launch_bounds__(256) void gemm_mfma(
    const bf16* __restrict__ Wb, const bf16* __restrict__ Bx,
    TY* __restrict__ Y, int MB, int wstride)
{
    constexpr int N = HW;
    const int b    = blockIdx.x & 7;
    const int slot = blockIdx.x >> 3;
    const int mb   = slot % MB;
    const int ng   = slot / MB;            // 0..127
    const int m0   = mb * 64;
    const int n0   = ng * 128;

    const char* Bpanel = (const char*)(Bx + (size_t)b * N * 192) + (size_t)n0 * 384;
    TY* Yb = Y + (size_t)b * (MB * 64) * N;

    __shared__ __align__(16) char Bs[49152];   // 128 rows x 384 B, swizzled

    const int tid  = threadIdx.x;
    const int lane = tid & 63, wave = tid >> 6;
    const int wm = (wave & 1) * 32, wn = (wave >> 1) * 64;
    const int r16 = lane & 15, quad = lane >> 4;

    // ---- stage B: 12 rounds x 4KB; source pre-swizzled (rule #21) ----
#pragma unroll
    for (int r = 0; r < 12; r++) {
        int L   = r * 4096 + tid * 16;         // linear LDS byte this lane fills
        int row = L / 384;
        int col = L - row * 384;
        int scol = col ^ ((row & 7) << 4);     // involution, stays in-row
        gload_lds16(Bpanel + (size_t)row * 384 + scol,
                    Bs + r * 4096 + wave * 1024);
    }

    // ---- A (weights) -> registers (L1/L2-hot, tiny) ----
    const bf16* aBase = Wb + (size_t)b * wstride
                      + (size_t)(m0 + wm + r16) * 192 + quad * 8;
    bf16x8 aReg[6][2];
#pragma unroll
    for (int ks = 0; ks < 6; ks++)
#pragma unroll
        for (int h = 0; h < 2; h++)
            aReg[ks][h] = *(const bf16x8*)(aBase + h * 16 * 192 + ks * 32);

    asm volatile("s_waitcnt vmcnt(0)" ::: "memory");   // drain gload_lds queue
    __syncthreads();

    f32x4 acc[2][4];
#pragma unroll
    for (int i = 0; i < 2; i++)
#pragma unroll
        for (int j = 0; j < 4; j++) acc[i][j] = (f32x4){0.f, 0.f, 0.f, 0.f};

    // per-sn row base + swizzle phase
    int rbase[4], rxor[4];
#pragma unroll
    for (int sn = 0; sn < 4; sn++) {
        int nl = wn + sn * 16 + r16;
        rbase[sn] = nl * 384;
        rxor[sn]  = (nl & 7) << 4;
    }

#pragma unroll
    for (int ks = 0; ks < 6; ks++) {
#pragma unroll
        for (int sn = 0; sn < 4; sn++) {
            bf16x8 bb = *(const bf16x8*)(
                Bs + rbase[sn] + ((ks * 64 + quad * 16) ^ rxor[sn]));
            acc[0][sn] = __builtin_amdgcn_mfma_f32_16x16x32_bf16(
                aReg[ks][0], bb, acc[0][sn], 0, 0, 0);
            acc[1][sn] = __builtin_amdgcn_mfma_f32_16x16x32_bf16(
                aReg[ks][1], bb, acc[1][sn], 0, 0, 0);
        }
    }

    // epilogue: C/D layout col=lane&15 (n), row=quad*4+reg (m) [m89/m91]
#pragma unroll
    for (int sm = 0; sm < 2; sm++)
#pragma unroll
        for (int sn = 0; sn < 4; sn++) {
            const int gr = m0 + wm + sm * 16 + quad * 4;
            const int gc = n0 + wn + sn * 16 + r16;
#pragma unroll
            for (int r = 0; r < 4; r++)
                stf(Yb + (size_t)(gr + r) * N + gc, acc[sm][sn][r]);
        }
}

// ============ K2: depthwise 3x3, pad 1 — LDS-tiled, vectorized ==============
__global__ __launch_bounds__(256) void dwconv3x3(
    const bf16* __restrict__ in, const float* __restrict__ wdw,
    bf16* __restrict__ out)
{
    const int plane = blockIdx.x >> 2;          // b*576 + c
    const int ybase = (blockIdx.x & 3) << 5;    // 0,32,64,96
    const int c = plane % 576;
    const bf16* ip = in + ((size_t)plane << 14);

    __shared__ unsigned short Ls[34][128];

    for (int i = threadIdx.x; i < 34 * 16; i += 256) {
        int r = i >> 4, cx = i & 15;
        int y = ybase - 1 + r;
        uint4 v = make_uint4(0u, 0u, 0u, 0u);
        if (y >= 0 && y < 128) v = ((const uint4*)(ip + ((size_t)y << 7)))[cx];
        ((uint4*)Ls[r])[cx] = v;
    }

    float w[9];
#pragma unroll
    for (int i = 0; i < 9; i++) w[i] = wdw[c * 9 + i];

    __syncthreads();

    const int lr = threadIdx.x >> 3;         // 0..31 output row
    const int c0 = (threadIdx.x & 7) << 4;   // 0,16,..,112

    float row[3][18];
#pragma unroll
    for (int r3 = 0; r3 < 3; r3++) {
        int rr = lr + r3;
        row[r3][0]  = c0 ? __uint_as_float((unsigned int)Ls[rr][c0 - 1] << 16) : 0.f;
        row[r3][17] = (c0 + 16 < 128) ? __uint_as_float((unsigned int)Ls[rr][c0 + 16] << 16) : 0.f;
        const uint4* rp = (const uint4*)&Ls[rr][c0];
        uint4 p0 = rp[0], p1 = rp[1];
        row[r3][1] = blo(p0.x); row[r3][2] = bhi(p0.x);
        row[r3][3] = blo(p0.y); row[r3][4] = bhi(p0.y);
        row[r3][5] = blo(p0.z); row[r3][6] = bhi(p0.z);
        row[r3][7] = blo(p0.w); row[r3][8] = bhi(p0.w);
        row[r3][9]  = blo(p1.x); row[r3][10] = bhi(p1.x);
        row[r3][11] = blo(p1.y); row[r3][12] = bhi(p1.y);
        row[r3][13] = blo(p1.z); row[r3][14] = bhi(p1.z);
        row[r3][15] = blo(p1.w); row[r3][16] = bhi(p1.w);
    }

    union { unsigned short s[16]; uint4 v[2]; } o;
#pragma unroll
    for (int j = 0; j < 16; j++) {
        float s = 0.f;
#pragma unroll
        for (int r3 = 0; r3 < 3; r3++)
            s += w[r3 * 3 + 0] * row[r3][j] + w[r3 * 3 + 1] * row[r3][j + 1]
               + w[r3 * 3 + 2] * row[r3][j + 2];
        o.s[j] = f2bu(s);
    }
    uint4* op = (uint4*)(out + ((size_t)plane << 14) + ((size_t)(ybase + lr) << 7) + c0);
    op[0] = o.v[0];
    op[1] = o.v[1];
}

// ============ K2b: transpose v-part: qkv1[b][384+c][hw] -> vT[b][hw][c] =====
// Pure layout change (bf16->bf16, no math) so the merged attn+proj GEMM can
// consume V with k-contiguous rows. tr_cast-style LDS transpose, coalesced
// on both sides.
__global__ __launch_bounds__(256) void vtrans(
    const bf16* __restrict__ qkv, bf16* __restrict__ vT)
{
    const int b  = blockIdx.x >> 8;
    const int t  = blockIdx.x & 255;
    const int hw0 = t << 6;                       // 64-col slab
    const bf16* vb = qkv + ((size_t)(b * 576 + 384) << 14);

    __shared__ unsigned short T[64][200];         // [hw][c]

    const int tid = threadIdx.x;
    for (int i = tid; i < 192 * 8; i += 256) {    // 192 rows x 8 uint4
        int c = i >> 3, ch = i & 7;
        uint4 u = *(const uint4*)(vb + ((size_t)c << 14) + hw0 + ch * 8);
        const unsigned short* us = (const unsigned short*)&u;
#pragma unroll
        for (int j = 0; j < 8; j++) T[ch * 8 + j][c] = us[j];
    }
    __syncthreads();

    const int hw = tid >> 2, c0 = (tid & 3) * 48; // 96 B per thread
    const uint4* src = (const uint4*)&T[hw][c0];
    uint4* dst = (uint4*)(vT + ((size_t)(b * HW) + hw0 + hw) * 192 + c0);
#pragma unroll
    for (int j = 0; j < 6; j++) dst[j] = src[j];
}

// ============ K3: per-row inverse L2 norm (q rows then k rows) ==============
__global__ __launch_bounds__(256) void rownorm(
    const bf16* __restrict__ qkv, float* __restrict__ rn)
{
    int r = blockIdx.x;
    int which = (r >= 1536) ? 1 : 0;
    int rr = r - which * 1536;
    int b = rr / 192, c = rr % 192;
    const bf16* p = qkv + ((size_t)(b * 576 + which * 192 + c) << 14);

    float s = 0.f;
    for (int i = threadIdx.x * 8; i < HW; i += 256 * 8) {
        float v[8];
        load8(p + i, v);
#pragma unroll
        for (int j = 0; j < 8; j++) s += v[j] * v[j];
    }
#pragma unroll
    for (int off = 32; off; off >>= 1) s += __shfl_down(s, off);
    __shared__ float red[4];
    if ((threadIdx.x & 63) == 0) red[threadIdx.x >> 6] = s;
    __syncthreads();
    if (threadIdx.x == 0) {
        float t = red[0] + red[1] + red[2] + red[3];
        rn[r] = 1.0f / fmaxf(sqrtf(t), 1e-12f);
    }
}

// ============ K4: raw dot products S[bh,c,d] = sum_n q[c,n]k[d,n] ===========
__global__ __launch_bounds__(256) void attn_dots(
    const bf16* __restrict__ qkv, float* __restrict__ attn)
{
    const int bh = blockIdx.y, b = bh >> 2, h = bh & 3;
    const int n0 = blockIdx.x * 1024;
    const bf16* q  = qkv + ((size_t)(b * 576 + h * 48) << 14);
    const bf16* kp = qkv + ((size_t)(b * 576 + 192 + h * 48) << 14);

    __shared__ float qt[48][68];
    __shared__ float kt[48][68];

    const int tid = threadIdx.x;
    const int cg = tid >> 4, dg = tid & 15;

    float acc[3][3] = {{0.f, 0.f, 0.f}, {0.f, 0.f, 0.f}, {0.f, 0.f, 0.f}};

    for (int s0 = 0; s0 < 1024; s0 += 64) {
        for (int i = tid; i < 48 * 8; i += 256) {
            int rowi = i / 8, cx = (i & 7) * 8;
            size_t off = ((size_t)rowi << 14) + n0 + s0 + cx;
            float v[8];
            load8(q + off, v);
#pragma unroll
            for (int j = 0; j < 8; j++) qt[rowi][cx + j] = v[j];
            load8(kp + off, v);
#pragma unroll
            for (int j = 0; j < 8; j++) kt[rowi][cx + j] = v[j];
        }
        __syncthreads();
#pragma unroll 8
        for (int n = 0; n < 64; n++) {
            float a0 = qt[cg * 3 + 0][n], a1 = qt[cg * 3 + 1][n], a2 = qt[cg * 3 + 2][n];
            float b0 = kt[dg * 3 + 0][n], b1 = kt[dg * 3 + 1][n], b2 = kt[dg * 3 + 2][n];
            acc[0][0] += a0 * b0; acc[0][1] += a0 * b1; acc[0][2] += a0 * b2;
            acc[1][0] += a1 * b0; acc[1][1] += a1 * b1; acc[1][2] += a1 * b2;
            acc[2][0] += a2 * b0; acc[2][1] += a2 * b1; acc[2][2] += a2 * b2;
        }
        __syncthreads();
    }
#pragma unroll
    for (int i = 0; i < 3; i++)
#pragma unroll
        for (int j = 0; j < 3; j++)
            atomicAdd(&attn[(size_t)bh * 2304 + (cg * 3 + i) * 48 + dg * 3 + j],
                      acc[i][j]);
}

// ============ K5: scale by norms & temperature, softmax over d ==============
__global__ __launch_bounds__(64) void softmax48(
    float* __restrict__ attn, const float* __restrict__ rn,
    const float* __restrict__ temp)
{
    int bh = blockIdx.x, b = bh >> 2, h = bh & 3;
    int c = threadIdx.x;
    if (c >= 48) return;
    float t = temp[h];
    float iq = rn[b * 192 + h * 48 + c];
    const float* ik = rn + 1536 + b * 192 + h * 48;
    float* row = attn + (size_t)bh * 2304 + c * 48;

    float v[48];
    float mx = -1e30f;
#pragma unroll
    for (int d = 0; d < 48; d++) {
        v[d] = row[d] * iq * ik[d] * t;
        mx = fmaxf(mx, v[d]);
    }
    float s = 0.f;
#pragma unroll
    for (int d = 0; d < 48; d++) {
        v[d] = expf(v[d] - mx);
        s += v[d];
    }
    float inv = 1.0f / s;
#pragma unroll
    for (int d = 0; d < 48; d++) row[d] = v[d] * inv;
}

// ============ K6: M_b = Pw @ blockdiag(A_b0..A_b3), f32 -> bf16 =============
// Associativity: out = Pw·(A·V) = (Pw·A)·V. M_b[i][h*48+d] =
// sum_c Pw[i][h*48+c] · A_bh[c][d]. 28 MFLOP total — replaces the entire
// 98us attn_v_t kernel; the merged GEMM consumes M_b with vT.
__global__ __launch_bounds__(192) void pwa(
    const float* __restrict__ pw, const float* __restrict__ attn,
    bf16* __restrict__ Mb)
{
    const int bh = blockIdx.x, b = bh >> 2, h = bh & 3;
    __shared__ float As[48 * 48];
    for (int i = threadIdx.x; i < 2304; i += 192)
        As[i] = attn[(size_t)bh * 2304 + i];
    __syncthreads();

    const int i = threadIdx.x;            // output row 0..191
    float p[48];
    const float* pr = pw + (size_t)i * 192 + h * 48;
#pragma unroll
    for (int j = 0; j < 12; j++) {
        float4 f = ((const float4*)pr)[j];
        p[4 * j] = f.x; p[4 * j + 1] = f.y; p[4 * j + 2] = f.z; p[4 * j + 3] = f.w;
    }
    float m[48];
#pragma unroll
    for (int d = 0; d < 48; d++) m[d] = 0.f;
#pragma unroll 4
    for (int c = 0; c < 48; c++) {
        float pc = p[c];
#pragma unroll
        for (int d = 0; d < 48; d++) m[d] += pc * As[c * 48 + d];
    }
    u32 pk[24];
#pragma unroll
    for (int j = 0; j < 24; j++)
        pk[j] = (u32)f2bu(m[2 * j]) | ((u32)f2bu(m[2 * j + 1]) << 16);
    uint4* o = (uint4*)(Mb + ((size_t)(b * 192) + i) * 192 + h * 48);
#pragma unroll
    for (int j = 0; j < 6; j++) o[j] = ((const uint4*)pk)[j];
}

// ============================================================================
extern "C" void kernel_launch(void* const* d_in, const int* in_sizes, int n_in,
                              void* d_out, int out_size, void* d_ws, size_t ws_size,
                              hipStream_t stream)
{
    const float* x      = (const float*)d_in[0];
    const float* qkv_w  = (const float*)d_in[1];
    const float* dw_w   = (const float*)d_in[2];
    const float* proj_w = (const float*)d_in[3];
    const float* temp   = (const float*)d_in[4];
    float* out = (float*)d_out;

    char* ws = (char*)d_ws;
    const size_t qkvBytes = (size_t)8 * 576 * HW * sizeof(bf16);  // 150,994,944 B
    bf16*  qkv0 = (bf16*)ws;                                  // pre-dw qkv
    bf16*  qkv1 = (bf16*)(ws + qkvBytes);                     // post-dw qkv
    float* attn = (float*)(ws + 2 * qkvBytes);                // 32*48*48 f32
    float* rn   = (float*)(ws + 2 * qkvBytes + (size_t)32 * 2304 * sizeof(float));

    // Aliases within the qkv0 region (151 MB; qkv0 content dead after dwconv):
    bf16* xT = (bf16*)qkv1;                        // dead once dwconv writes qkv1
    bf16* vT = (bf16*)ws;                          // [0, 50.3 MB)
    bf16* Mb = (bf16*)(ws + 104 * 1024 * 1024);    // 0.59 MB, disjoint from vT
    bf16* Wb = (bf16*)attn;                        // 221 KB; dead before memset

    // 0) transpose+cast x -> xT bf16 [b][n][k]
    tr_cast<<<dim3(8 * 256), 256, 0, stream>>>(x, xT);
    // 0b) cast qkv weights -> bf16
    wcast<<<dim3(108), 256, 0, stream>>>(qkv_w, Wb, 27648);
    // 1) qkv 1x1 conv (gload_lds MFMA): (576x192) @ (192x16384) per batch
    gemm_mfma<bf16><<<dim3(8 * 9 * 128), 256, 0, stream>>>(Wb, xT, qkv0, 9, 0);
    // 2) depthwise 3x3 (LDS-tiled); overwrites xT region (dead)
    dwconv3x3<<<dim3(8 * 576 * 4), 256, 0, stream>>>(qkv0, dw_w, qkv1);
    // 2b) transpose v-part -> vT [b][n][192] (qkv0 region now dead)
    vtrans<<<dim3(8 * 256), 256, 0, stream>>>(qkv1, vT);
    // 3) inverse L2 norms for q and k rows
    rownorm<<<dim3(3072), 256, 0, stream>>>(qkv1, rn);
    // 4) attention dots (f32 atomics into zeroed buffer); clobbers Wb (dead)
    hipMemsetAsync(attn, 0, (size_t)32 * 2304 * sizeof(float), stream);
    attn_dots<<<dim3(16, 32), 256, 0, stream>>>(qkv1, attn);
    // 5) scale + softmax
    softmax48<<<dim3(32), 64, 0, stream>>>(attn, rn, temp);
    // 6) M_b = Pw @ blockdiag(A) -> bf16 per-batch weights
    pwa<<<dim3(32), 192, 0, stream>>>(proj_w, attn, Mb);
    // 7) merged attn+proj GEMM: out[b] = M_b(192x192) @ vT[b](192x16384)
    gemm_mfma<float><<<dim3(8 * 3 * 128), 256, 0, stream>>>(
        Mb, vT, out, 3, 192 * 192);
}